// Round 9
// baseline (295.609 us; speedup 1.0000x reference)
//
#include <hip/hip_runtime.h>
#include <hip/hip_bf16.h>

// Problem constants (match reference)
#define NPTS 400000          // == 6250 * 64 exactly
#define NVOX 100000
#define EPSB 1e-3f
#define NTILE 6250
#define NBLK_SCAN 391        // ceil(NVOX/256)
#define GBLK 782             // k_prep grid (2-3 pts/thread)

// ws layout (in floats) — ~108 MB
#define OFF_ACC4   0                          // 4*NVOX [cnt,sx,sy,sz]
#define OFF_GRAM   (4*NVOX)                   // 72: sx[10]+sxx[55]
#define OFF_P1     (OFF_GRAM + 128)           // 32 slots * 128
#define ZERO_FLOATS (OFF_P1 + 4096)           // zeroed prefix (~1.6 MB)
#define OFF_V0     ZERO_FLOATS                // NVOX*64 fp32 h0 max (tile-spanning rows zeroed by scan3)
#define OFF_Y1M    (OFF_V0 + NVOX*64)         // NVOX*64 raw y1 max (fkey; window-spanning rows zeroed)
#define OFF_VTMP   (OFF_Y1M + NVOX*64)        // NVOX
#define OFF_BSUM   (OFF_VTMP + NVOX)          // 512
#define OFF_VOFF   (OFF_BSUM + 512)           // NVOX (scatter cursors)
#define OFF_VSTART (OFF_VOFF + NVOX)          // NVOX+8 (+ sentinel)
#define OFF_ORD    (OFF_VSTART + NVOX + 8)    // NPTS
#define OFF_VS     (OFF_ORD + NPTS)           // NPTS (vsorted, sequential fill by scan3)
#define OFF_W0F    (OFF_VS + NPTS)            // 640
#define OFF_W1B    (OFF_W0F + 640)            // 4096 floats = 8192 bf16
#define OFF_H0T    (OFF_W1B + 4096)           // NPTS*64 bf16 (sorted h0 tiles)

#define XTB_LD 136
#define HT_LD  65

typedef __bf16 bf16x8 __attribute__((ext_vector_type(8)));
typedef float  f32x4  __attribute__((ext_vector_type(4)));

__device__ __forceinline__ float b2f(__hip_bfloat16 h) { return __bfloat162float(h); }
__device__ __forceinline__ float bfbits2f(unsigned short u) {
    return __uint_as_float((unsigned int)u << 16);
}
__device__ __forceinline__ unsigned short bf16u(float f) {
    __hip_bfloat16 h = __float2bfloat16(f);
    return __builtin_bit_cast(unsigned short, h);
}
__device__ __forceinline__ unsigned int fkey(float f) {
    unsigned int u = __float_as_uint(f);
    return (u & 0x80000000u) ? ~u : (u | 0x80000000u);
}
__device__ __forceinline__ float funkey(unsigned int k) {
    unsigned int u = (k & 0x80000000u) ? (k & 0x7FFFFFFFu) : ~k;
    return __uint_as_float(u);
}

__device__ __forceinline__ void compute_x(const __hip_bfloat16* __restrict__ feat,
                                          const float* __restrict__ acc4,
                                          const int* __restrict__ coors,
                                          long i, int v, float* xv) {
    ushort4 f4 = *(const ushort4*)(feat + 4 * i);
    float px = bfbits2f(f4.x), py = bfbits2f(f4.y), pz = bfbits2f(f4.z), it = bfbits2f(f4.w);
    float4 a4 = *(const float4*)&acc4[4 * (long)v];
    float ic = 1.0f / a4.x;
    int4 c4 = *(const int4*)&coors[4 * (long)v];   // (b, z, y, x)
    xv[0] = px; xv[1] = py; xv[2] = pz;
    xv[3] = px - a4.y * ic; xv[4] = py - a4.z * ic; xv[5] = pz - a4.w * ic;
    xv[6] = px - ((float)c4.w * 0.2f + 0.1f);
    xv[7] = py - ((float)c4.z * 0.2f + 0.1f - 40.0f);
    xv[8] = pz - ((float)c4.y * 4.0f + 2.0f - 3.0f);
    xv[9] = it;
}

// ---- K1: per-voxel count + xyz sums; last block converts weights
// (W0 -> fp32; W1 -> bf16 MFMA B-fragment order). ----
__global__ void k_vsum(const __hip_bfloat16* __restrict__ feat,
                       const int* __restrict__ inv,
                       float* __restrict__ acc4,
                       const __hip_bfloat16* __restrict__ W0,
                       const __hip_bfloat16* __restrict__ W1,
                       float* __restrict__ W0f, unsigned short* __restrict__ w1b) {
    if (blockIdx.x == 6250) {
        int t = threadIdx.x;
        for (int j = t; j < 640; j += 256) W0f[j] = b2f(W0[j]);
        for (int f = t; f < 8192; f += 256) {
            int j  = f & 7;
            int l  = (f >> 3) & 63;
            int ks = (f >> 9) & 3;
            int ct = f >> 11;
            int ch = ct * 16 + (l & 15);
            int k  = ks * 32 + ((l >> 4) & 3) * 8 + j;
            w1b[f] = __builtin_bit_cast(unsigned short, W1[ch * 128 + k]);
        }
        return;
    }
    long t = (long)blockIdx.x * 256 + threadIdx.x;
    int pt = (int)(t >> 2);
    int comp = (int)(t & 3);
    float val = (comp == 0) ? 1.0f : b2f(feat[4 * pt + comp - 1]);
    int v = inv[pt];
    atomicAdd(&acc4[(long)v * 4 + comp], val);
}

// ---- prefix scan of voxel counts ----
__global__ void k_scan1(const float* __restrict__ acc4,
                        int* __restrict__ vtmp, int* __restrict__ bsum) {
    __shared__ int sc[256];
    int b = blockIdx.x, t = threadIdx.x;
    int v = b * 256 + t;
    int c = (v < NVOX) ? (int)acc4[4 * (long)v] : 0;
    sc[t] = c;
    __syncthreads();
    int val = c;
    for (int off = 1; off < 256; off <<= 1) {
        int x = (t >= off) ? sc[t - off] : 0;
        __syncthreads();
        val += x; sc[t] = val;
        __syncthreads();
    }
    if (v < NVOX) vtmp[v] = val - c;
    if (t == 255) bsum[b] = val;
}

__global__ void k_scan2(int* __restrict__ bsum) {
    __shared__ int sc[512];
    int t = threadIdx.x;
    int c = (t < NBLK_SCAN) ? bsum[t] : 0;
    sc[t] = c;
    __syncthreads();
    int val = c;
    for (int off = 1; off < 512; off <<= 1) {
        int x = (t >= off) ? sc[t - off] : 0;
        __syncthreads();
        val += x; sc[t] = val;
        __syncthreads();
    }
    if (t < NBLK_SCAN) bsum[t] = val - c;
}

// ---- scan3: finalize offsets; fill vsorted by sequential per-voxel runs;
// zero-init y1m rows for WINDOW-spanning voxels (k_mfma's atomic path) and
// v0 rows for TILE-spanning voxels (the only ones k_h0max writes now). ----
__global__ void k_scan3(const int* __restrict__ vtmp, const int* __restrict__ bsum,
                        int* __restrict__ voff, int* __restrict__ vstart,
                        int* __restrict__ vsorted,
                        float* __restrict__ v0, unsigned int* __restrict__ y1m) {
    int v = blockIdx.x * 256 + threadIdx.x;
    if (v < NVOX) {
        int s0 = vtmp[v] + bsum[v >> 8];
        voff[v] = s0;
        vstart[v] = s0;
        int s1;
        if (v + 1 < NVOX) s1 = vtmp[v + 1] + bsum[(v + 1) >> 8];
        else              s1 = NPTS;
        for (int j = s0; j < s1; j++) vsorted[j] = v;
        float4 z4 = {0.f, 0.f, 0.f, 0.f};
        if ((s0 >> 4) != ((s1 - 1) >> 4)) {   // spans a 16-pt window boundary
            float4* py = (float4*)&y1m[(long)v * 64];
#pragma unroll
            for (int u = 0; u < 16; u++) py[u] = z4;
        }
        if ((s0 >> 6) != ((s1 - 1) >> 6)) {   // spans a 64-pt tile boundary
            float4* pv = (float4*)&v0[(long)v * 64];
#pragma unroll
            for (int u = 0; u < 16; u++) pv[u] = z4;
        }
    }
    if (v == 0) vstart[NVOX] = NPTS;
}

// ---- K2: Gram stats (in-register, fully unrolled) + counting-sort scatter
// of ONLY the point index (4B/pt; vsorted comes from scan3's streaming fill).
__global__ __launch_bounds__(256, 4)
void k_prep(const __hip_bfloat16* __restrict__ feat,
            const int* __restrict__ inv,
            const int* __restrict__ coors,
            const float* __restrict__ acc4,
            int* __restrict__ voff,
            int* __restrict__ ord,
            float* __restrict__ gram) {
    __shared__ float gs[72];
    int t = threadIdx.x;
    if (t < 72) gs[t] = 0.0f;
    __syncthreads();

    float sx[10], sxx[55];
#pragma unroll
    for (int a = 0; a < 10; a++) sx[a] = 0.0f;
#pragma unroll
    for (int a = 0; a < 55; a++) sxx[a] = 0.0f;

    for (long i = (long)blockIdx.x * 256 + t; i < NPTS; i += (long)GBLK * 256) {
        int v = inv[i];
        float xv[10];
        compute_x(feat, acc4, coors, i, v, xv);
        int idx = 0;
#pragma unroll
        for (int a = 0; a < 10; a++) {
            sx[a] += xv[a];
#pragma unroll
            for (int b = 0; b <= a; b++) sxx[idx++] += xv[a] * xv[b];
        }
        int pos = atomicAdd(&voff[v], 1);
        ord[pos] = (int)i;
    }

#pragma unroll
    for (int v = 0; v < 65; v++) {
        float s = (v < 10) ? sx[v] : sxx[v - 10];
        for (int m = 32; m >= 1; m >>= 1) s += __shfl_xor(s, m);
        if ((t & 63) == 0) atomicAdd(&gs[v], s);
    }
    __syncthreads();
    if (t < 65) atomicAdd(&gram[t], gs[t]);
}

// ---- K3: h0 = relu(bn0(y0)); sorted tile; wave 1 folds the BN0 finalize
// into LDS. Spills the h0 tile (bf16, sorted layout) for layer 1. v0 is
// written ONLY for tile-spanning voxels (~2/tile) — tile-complete voxel
// maxima are reconstructed in-LDS by k_mfma_stats from the h0 tile. ----
__global__ __launch_bounds__(256, 6)
void k_h0max(const int* __restrict__ ord, const int* __restrict__ vsorted,
             const int* __restrict__ vstart,
             const __hip_bfloat16* __restrict__ feat,
             const float* __restrict__ acc4, const int* __restrict__ coors,
             const float* __restrict__ W0f, const float* __restrict__ gram,
             const __hip_bfloat16* __restrict__ g0,
             const __hip_bfloat16* __restrict__ be0,
             float* __restrict__ v0, unsigned short* __restrict__ h0t) {
    __shared__ float ht[64 * HT_LD];      // 16640 B
    __shared__ int invs[64];
    __shared__ float sc0s[64], bi0s[64];  // total ~17.4 KB
    int t = threadIdx.x, w = t >> 6, l = t & 63;
    int base = blockIdx.x * 64;
    int i = ord[base + l];
    int v = vsorted[base + l];
    if (w == 0) invs[l] = v;

    float xv[10];
    compute_x(feat, acc4, coors, (long)i, v, xv);

    if (w == 1) {
        // BN0 finalize from Gram (per-block redundant, ~100 FMA — trivial)
        int c = l;
        float wr[10];
#pragma unroll
        for (int k = 0; k < 10; k++) wr[k] = W0f[c * 10 + k];
        float sum = 0.0f, sq = 0.0f;
#pragma unroll
        for (int a = 0; a < 10; a++) {
            sum += wr[a] * gram[a];
            float ta = 0.0f;
#pragma unroll
            for (int b = 0; b < 10; b++) {
                int hi = (a >= b) ? a : b, lo = (a >= b) ? b : a;
                ta += wr[b] * gram[10 + hi * (hi + 1) / 2 + lo];
            }
            sq += wr[a] * ta;
        }
        float mu  = sum * (1.0f / NPTS);
        float var = sq * (1.0f / NPTS) - mu * mu;
        float g   = b2f(g0[c]) * rsqrtf(var + EPSB);
        sc0s[c] = g;
        bi0s[c] = b2f(be0[c]) - mu * g;
    }
    __syncthreads();

    int cw = w * 16;
#pragma unroll
    for (int j = 0; j < 16; j++) {
        int c = cw + j;
        float y = 0.0f;
#pragma unroll
        for (int k = 0; k < 10; k++) y += xv[k] * W0f[c*10 + k];
        ht[l * HT_LD + c] = fmaxf(sc0s[c] * y + bi0s[c], 0.0f);
    }
    __syncthreads();

    // spill h0 tile (bf16, sorted layout)
#pragma unroll
    for (int u = 0; u < 2; u++) {
        int idx = t + u * 256;          // 0..511, coalesced uint4 per thread
        int pt2 = idx >> 3;
        int c0 = (idx & 7) * 8;
        const float* src = &ht[pt2 * HT_LD + c0];
        float4 a  = *(const float4*)src;
        float4 b4 = *(const float4*)(src + 4);
        uint4 o;
        o.x = (unsigned int)bf16u(a.x)  | ((unsigned int)bf16u(a.y)  << 16);
        o.y = (unsigned int)bf16u(a.z)  | ((unsigned int)bf16u(a.w)  << 16);
        o.z = (unsigned int)bf16u(b4.x) | ((unsigned int)bf16u(b4.y) << 16);
        o.w = (unsigned int)bf16u(b4.z) | ((unsigned int)bf16u(b4.w) << 16);
        *(uint4*)&h0t[(long)(base + pt2) * 64 + c0] = o;
    }

    // lane = channel; wave walks its 16 sorted points; only TILE-spanning
    // voxels need the global partial max (zero-init'd rows, h0 >= 0).
    unsigned int mk = 0u;
#pragma unroll
    for (int j = 0; j < 16; j++) {
        int p = cw + j;
        unsigned int hb = __float_as_uint(ht[p * HT_LD + l]);
        mk = (hb > mk) ? hb : mk;
        if (j == 15 || invs[p + 1] != invs[p]) {
            int vv = invs[p];
            int s0 = vstart[vv], s1 = vstart[vv + 1];
            if (s0 < base || s1 > base + 64)
                atomicMax((unsigned int*)&v0[(long)vv * 64 + l], mk);
            mk = 0u;
        }
    }
}

// ---- K4: layer-1 MFMA over sorted tiles. h0 half of x1 is a coalesced tile
// copy from h0t; the v0 half is RECONSTRUCTED IN-LDS by a run-combine walk
// over the bf16 tile (max(bf16) == bf16(max), rounding is monotone); only
// tile-spanning voxels (~2/tile) read the global v0 row. ----
__global__ __launch_bounds__(256, 6)
void k_mfma_stats(const int* __restrict__ vsorted,
                  const int* __restrict__ vstart,
                  const unsigned short* __restrict__ h0t,
                  const unsigned short* __restrict__ w1b,
                  const float* __restrict__ v0,
                  float* __restrict__ P1,
                  unsigned int* __restrict__ y1m) {
    __shared__ union {
        unsigned short xtb[64 * XTB_LD];
        float ht[64 * HT_LD];
    } sm;
    __shared__ int invs[64];
    int t = threadIdx.x, w = t >> 6, l = t & 63;
    int quad = l >> 4, lm = l & 15;
    int base = blockIdx.x * 64;
    if (w == 0) invs[l] = vsorted[base + l];

    bf16x8 bfrag[4];
    const uint4* wf = (const uint4*)w1b;
#pragma unroll
    for (int ks = 0; ks < 4; ks++)
        bfrag[ks] = __builtin_bit_cast(bf16x8, wf[(w * 4 + ks) * 64 + l]);

    // ---- stage x1 lower half (bf16 [pt][k]): coalesced tile copy ----
#pragma unroll
    for (int u = 0; u < 2; u++) {
        int idx = t + u * 256;
        int pt = idx >> 3, c0 = (idx & 7) * 8;
        uint4 d = *(const uint4*)&h0t[(long)(base + pt) * 64 + c0];
        *(uint4*)&sm.xtb[pt * XTB_LD + c0] = d;
    }
    __syncthreads();

    // ---- upper half: voxel max via run-combine walk (lane = channel).
    // Each wave walks all 64 points (reads 2B/lane, 2 lanes/bank = free)
    // and writes only its own 16 rows. bf16 bits of h0>=0 compare as u16. ----
    {
        unsigned short vmax = 0;
        int p0 = 0;
        int cw = w * 16;
        for (int p = 0; p < 64; p++) {
            unsigned short hb = sm.xtb[p * XTB_LD + l];
            vmax = (hb > vmax) ? hb : vmax;
            if (p == 63 || invs[p + 1] != invs[p]) {
                int vv = invs[p];
                int s0v = vstart[vv], s1v = vstart[vv + 1];
                if (s0v < base || s1v > base + 64)
                    vmax = bf16u(v0[(long)vv * 64 + l]);   // final global max
                int lo = (p0 > cw) ? p0 : cw;
                int hi = (p < cw + 15) ? p : (cw + 15);
                for (int q = lo; q <= hi; q++)
                    sm.xtb[q * XTB_LD + 64 + l] = vmax;
                vmax = 0; p0 = p + 1;
            }
        }
    }
    __syncthreads();

    // ---- MFMA ----
    f32x4 acc[4];
#pragma unroll
    for (int pg = 0; pg < 4; pg++) acc[pg] = (f32x4){0.f, 0.f, 0.f, 0.f};
#pragma unroll
    for (int ks = 0; ks < 4; ks++) {
#pragma unroll
        for (int pg = 0; pg < 4; pg++) {
            const uint4* ap = (const uint4*)&sm.xtb[(pg * 16 + lm) * XTB_LD + ks * 32 + quad * 8];
            bf16x8 a = __builtin_bit_cast(bf16x8, *ap);
            acc[pg] = __builtin_amdgcn_mfma_f32_16x16x32_bf16(a, bfrag[ks], acc[pg], 0, 0, 0);
        }
    }

    // ---- stats from accumulators ----
    float ssum = 0.0f, ssq = 0.0f;
#pragma unroll
    for (int pg = 0; pg < 4; pg++) {
#pragma unroll
        for (int r = 0; r < 4; r++) {
            float y = acc[pg][r];
            ssum += y; ssq += y * y;
        }
    }
    __syncthreads();   // all xtb reads done -> safe to overwrite with ht

    // raw y1 -> LDS transpose (C layout: row = quad*4+r, col = lm)
#pragma unroll
    for (int pg = 0; pg < 4; pg++) {
#pragma unroll
        for (int r = 0; r < 4; r++)
            sm.ht[(pg * 16 + quad * 4 + r) * HT_LD + w * 16 + lm] = acc[pg][r];
    }
    __syncthreads();

    // lane = channel; wave walks its 16 sorted points; plain-store/atomic split
    unsigned int mk = 0u;
    int cw = w * 16;
#pragma unroll
    for (int j = 0; j < 16; j++) {
        int p = cw + j;
        unsigned int k2 = fkey(sm.ht[p * HT_LD + l]);
        mk = (k2 > mk) ? k2 : mk;
        if (j == 15 || invs[p + 1] != invs[p]) {
            int vv = invs[p];
            int s0 = vstart[vv], s1 = vstart[vv + 1];
            unsigned int* dst = &y1m[(long)vv * 64 + l];
            if (s0 >= base + cw && s1 <= base + cw + 16)
                *dst = mk;
            else
                atomicMax(dst, mk);
            mk = 0u;
        }
    }

    ssum += __shfl_xor(ssum, 16); ssq += __shfl_xor(ssq, 16);
    ssum += __shfl_xor(ssum, 32); ssq += __shfl_xor(ssq, 32);
    if (l < 16) {
        int slot = blockIdx.x & 31;
        atomicAdd(&P1[slot * 128 + w * 16 + lm], ssum);
        atomicAdd(&P1[slot * 128 + 64 + w * 16 + lm], ssq);
    }
}

// ---- K5: emit output with INLINE BN1 finalize (per-block redundant P1 reduce).
// feats = relu(bn1(decode(y1max))); coors bf16-rounded. Grid-stride, 512 blocks.
#define OUTBLK 512
__global__ __launch_bounds__(256)
void k_out(const unsigned int* __restrict__ y1m,
           const float* __restrict__ P1,
           const __hip_bfloat16* __restrict__ gamma,
           const __hip_bfloat16* __restrict__ beta,
           const int* __restrict__ coors,
           float* __restrict__ out) {
    __shared__ float sc1s[64], bi1s[64];
    int t = threadIdx.x;
    if (t < 64) {
        float sum = 0.0f, sq = 0.0f;
        for (int s = 0; s < 32; s++) {
            sum += P1[s*128 + t];
            sq  += P1[s*128 + 64 + t];
        }
        float mu  = sum * (1.0f / NPTS);
        float var = sq * (1.0f / NPTS) - mu * mu;
        float g   = b2f(gamma[t]) * rsqrtf(var + EPSB);
        sc1s[t] = g;
        bi1s[t] = b2f(beta[t]) - mu * g;
    }
    __syncthreads();

    const long n4feat = (long)NVOX * 16;   // uint4 chunks of y1m
    const long n4all  = n4feat + NVOX;     // + int4 chunks of coors
    const long nfeat  = (long)NVOX * 64;
    for (long idx = (long)blockIdx.x * 256 + t; idx < n4all; idx += (long)OUTBLK * 256) {
        if (idx < n4feat) {
            uint4 kk = ((const uint4*)y1m)[idx];
            int c0 = (int)((idx * 4) & 63);
            float4 o;
            o.x = fmaxf(sc1s[c0+0] * funkey(kk.x) + bi1s[c0+0], 0.0f);
            o.y = fmaxf(sc1s[c0+1] * funkey(kk.y) + bi1s[c0+1], 0.0f);
            o.z = fmaxf(sc1s[c0+2] * funkey(kk.z) + bi1s[c0+2], 0.0f);
            o.w = fmaxf(sc1s[c0+3] * funkey(kk.w) + bi1s[c0+3], 0.0f);
            ((float4*)out)[idx] = o;
        } else {
            long vi = idx - n4feat;
            int4 c4 = ((const int4*)coors)[vi];
            float4 o;
            o.x = b2f(__float2bfloat16((float)c4.x));
            o.y = b2f(__float2bfloat16((float)c4.y));
            o.z = b2f(__float2bfloat16((float)c4.z));
            o.w = b2f(__float2bfloat16((float)c4.w));
            ((float4*)(out + nfeat))[vi] = o;
        }
    }
}

extern "C" void kernel_launch(void* const* d_in, const int* in_sizes, int n_in,
                              void* d_out, int out_size, void* d_ws, size_t ws_size,
                              hipStream_t stream) {
    const __hip_bfloat16* feat = (const __hip_bfloat16*)d_in[0];
    const __hip_bfloat16* W0   = (const __hip_bfloat16*)d_in[1];
    const __hip_bfloat16* g0   = (const __hip_bfloat16*)d_in[2];
    const __hip_bfloat16* be0  = (const __hip_bfloat16*)d_in[3];
    const __hip_bfloat16* W1   = (const __hip_bfloat16*)d_in[4];
    const __hip_bfloat16* g1   = (const __hip_bfloat16*)d_in[5];
    const __hip_bfloat16* be1  = (const __hip_bfloat16*)d_in[6];
    const int* inv   = (const int*)d_in[7];
    const int* coors = (const int*)d_in[8];
    float* out = (float*)d_out;

    float* ws    = (float*)d_ws;
    float* acc4  = ws + OFF_ACC4;
    float* gram  = ws + OFF_GRAM;
    float* P1    = ws + OFF_P1;
    float* v0    = ws + OFF_V0;
    unsigned int* y1m = (unsigned int*)(ws + OFF_Y1M);
    int* vtmp    = (int*)(ws + OFF_VTMP);
    int* bsum    = (int*)(ws + OFF_BSUM);
    int* voff    = (int*)(ws + OFF_VOFF);
    int* vstart  = (int*)(ws + OFF_VSTART);
    int* ord     = (int*)(ws + OFF_ORD);
    int* vsorted = (int*)(ws + OFF_VS);
    float* W0f   = ws + OFF_W0F;
    unsigned short* w1b = (unsigned short*)(ws + OFF_W1B);
    unsigned short* h0t = (unsigned short*)(ws + OFF_H0T);

    // Only atomic-accumulated buffers need zeroing (acc4, gram, P1);
    // v0/y1m spanning rows are zeroed selectively by k_scan3.
    hipMemsetAsync(ws, 0, (size_t)ZERO_FLOATS * sizeof(float), stream);

    k_vsum<<<6251, 256, 0, stream>>>(feat, inv, acc4, W0, W1, W0f, w1b);
    k_scan1<<<NBLK_SCAN, 256, 0, stream>>>(acc4, vtmp, bsum);
    k_scan2<<<1, 512, 0, stream>>>(bsum);
    k_scan3<<<NBLK_SCAN, 256, 0, stream>>>(vtmp, bsum, voff, vstart, vsorted, v0, y1m);
    k_prep<<<GBLK, 256, 0, stream>>>(feat, inv, coors, acc4, voff, ord, gram);
    k_h0max<<<NTILE, 256, 0, stream>>>(ord, vsorted, vstart, feat, acc4, coors,
                                       W0f, gram, g0, be0, v0, h0t);
    k_mfma_stats<<<NTILE, 256, 0, stream>>>(vsorted, vstart, h0t, w1b, v0, P1, y1m);
    k_out<<<OUTBLK, 256, 0, stream>>>(y1m, P1, g1, be1, coors, out);
}

// Round 10
// 258.432 us; speedup vs baseline: 1.1439x; 1.1439x over previous
//
#include <hip/hip_runtime.h>
#include <hip/hip_bf16.h>

// Problem constants (match reference)
#define NPTS 400000          // == 6250 * 64 exactly
#define NVOX 100000
#define EPSB 1e-3f
#define NTILE 6250
#define NBLK_SCAN 391        // ceil(NVOX/256)
#define GBLK 782             // k_prep grid (2-3 pts/thread)

// ws layout (in floats) — ~120 MB
#define OFF_ACC4   0                          // 4*NVOX [cnt,sx,sy,sz]
#define OFF_GRAM   (4*NVOX)                   // 72: sx[10]+sxx[55]
#define OFF_P1     (OFF_GRAM + 128)           // 32 slots * 128
#define ZERO_FLOATS (OFF_P1 + 4096)           // zeroed prefix (~1.6 MB)
#define OFF_V0     ZERO_FLOATS                // NVOX*64 fp32 h0 max (ONLY window-spanning voxels; rows zeroed by scan3)
#define OFF_Y1M    (OFF_V0 + NVOX*64)         // NVOX*64 raw y1 max (fkey; window-spanning rows zeroed)
#define OFF_VTMP   (OFF_Y1M + NVOX*64)        // NVOX
#define OFF_BSUM   (OFF_VTMP + NVOX)          // 512
#define OFF_VOFF   (OFF_BSUM + 512)           // NVOX (scatter cursors)
#define OFF_VSTART (OFF_VOFF + NVOX)          // NVOX+8 (+ sentinel)
#define OFF_ORD    (OFF_VSTART + NVOX + 8)    // NPTS
#define OFF_VS     (OFF_ORD + NPTS)           // NPTS (vsorted, sequential fill by scan3)
#define OFF_W0F    (OFF_VS + NPTS)            // 640
#define OFF_W1B    (OFF_W0F + 640)            // 4096 floats = 8192 bf16
#define OFF_H0T    (OFF_W1B + 4096)           // NPTS*64 bf16 (sorted h0 tiles)
#define OFF_V0B    (OFF_H0T + NPTS*32)        // NVOX*64 bf16 (window-complete voxels, final bf16 max)

#define XTB_LD 136
#define HT_LD  65

typedef __bf16 bf16x8 __attribute__((ext_vector_type(8)));
typedef float  f32x4  __attribute__((ext_vector_type(4)));

__device__ __forceinline__ float b2f(__hip_bfloat16 h) { return __bfloat162float(h); }
__device__ __forceinline__ float bfbits2f(unsigned short u) {
    return __uint_as_float((unsigned int)u << 16);
}
__device__ __forceinline__ unsigned short bf16u(float f) {
    __hip_bfloat16 h = __float2bfloat16(f);
    return __builtin_bit_cast(unsigned short, h);
}
__device__ __forceinline__ unsigned int fkey(float f) {
    unsigned int u = __float_as_uint(f);
    return (u & 0x80000000u) ? ~u : (u | 0x80000000u);
}
__device__ __forceinline__ float funkey(unsigned int k) {
    unsigned int u = (k & 0x80000000u) ? (k & 0x7FFFFFFFu) : ~k;
    return __uint_as_float(u);
}

__device__ __forceinline__ void compute_x(const __hip_bfloat16* __restrict__ feat,
                                          const float* __restrict__ acc4,
                                          const int* __restrict__ coors,
                                          long i, int v, float* xv) {
    ushort4 f4 = *(const ushort4*)(feat + 4 * i);
    float px = bfbits2f(f4.x), py = bfbits2f(f4.y), pz = bfbits2f(f4.z), it = bfbits2f(f4.w);
    float4 a4 = *(const float4*)&acc4[4 * (long)v];
    float ic = 1.0f / a4.x;
    int4 c4 = *(const int4*)&coors[4 * (long)v];   // (b, z, y, x)
    xv[0] = px; xv[1] = py; xv[2] = pz;
    xv[3] = px - a4.y * ic; xv[4] = py - a4.z * ic; xv[5] = pz - a4.w * ic;
    xv[6] = px - ((float)c4.w * 0.2f + 0.1f);
    xv[7] = py - ((float)c4.z * 0.2f + 0.1f - 40.0f);
    xv[8] = pz - ((float)c4.y * 4.0f + 2.0f - 3.0f);
    xv[9] = it;
}

// ---- K1: per-voxel count + xyz sums; last block converts weights
// (W0 -> fp32; W1 -> bf16 MFMA B-fragment order). ----
__global__ void k_vsum(const __hip_bfloat16* __restrict__ feat,
                       const int* __restrict__ inv,
                       float* __restrict__ acc4,
                       const __hip_bfloat16* __restrict__ W0,
                       const __hip_bfloat16* __restrict__ W1,
                       float* __restrict__ W0f, unsigned short* __restrict__ w1b) {
    if (blockIdx.x == 6250) {
        int t = threadIdx.x;
        for (int j = t; j < 640; j += 256) W0f[j] = b2f(W0[j]);
        for (int f = t; f < 8192; f += 256) {
            int j  = f & 7;
            int l  = (f >> 3) & 63;
            int ks = (f >> 9) & 3;
            int ct = f >> 11;
            int ch = ct * 16 + (l & 15);
            int k  = ks * 32 + ((l >> 4) & 3) * 8 + j;
            w1b[f] = __builtin_bit_cast(unsigned short, W1[ch * 128 + k]);
        }
        return;
    }
    long t = (long)blockIdx.x * 256 + threadIdx.x;
    int pt = (int)(t >> 2);
    int comp = (int)(t & 3);
    float val = (comp == 0) ? 1.0f : b2f(feat[4 * pt + comp - 1]);
    int v = inv[pt];
    atomicAdd(&acc4[(long)v * 4 + comp], val);
}

// ---- prefix scan of voxel counts ----
__global__ void k_scan1(const float* __restrict__ acc4,
                        int* __restrict__ vtmp, int* __restrict__ bsum) {
    __shared__ int sc[256];
    int b = blockIdx.x, t = threadIdx.x;
    int v = b * 256 + t;
    int c = (v < NVOX) ? (int)acc4[4 * (long)v] : 0;
    sc[t] = c;
    __syncthreads();
    int val = c;
    for (int off = 1; off < 256; off <<= 1) {
        int x = (t >= off) ? sc[t - off] : 0;
        __syncthreads();
        val += x; sc[t] = val;
        __syncthreads();
    }
    if (v < NVOX) vtmp[v] = val - c;
    if (t == 255) bsum[b] = val;
}

__global__ void k_scan2(int* __restrict__ bsum) {
    __shared__ int sc[512];
    int t = threadIdx.x;
    int c = (t < NBLK_SCAN) ? bsum[t] : 0;
    sc[t] = c;
    __syncthreads();
    int val = c;
    for (int off = 1; off < 512; off <<= 1) {
        int x = (t >= off) ? sc[t - off] : 0;
        __syncthreads();
        val += x; sc[t] = val;
        __syncthreads();
    }
    if (t < NBLK_SCAN) bsum[t] = val - c;
}

// ---- scan3: finalize offsets; fill vsorted by sequential per-voxel runs;
// zero-init v0/y1m rows ONLY for window-spanning voxels (atomic paths). ----
__global__ void k_scan3(const int* __restrict__ vtmp, const int* __restrict__ bsum,
                        int* __restrict__ voff, int* __restrict__ vstart,
                        int* __restrict__ vsorted,
                        float* __restrict__ v0, unsigned int* __restrict__ y1m) {
    int v = blockIdx.x * 256 + threadIdx.x;
    if (v < NVOX) {
        int s0 = vtmp[v] + bsum[v >> 8];
        voff[v] = s0;
        vstart[v] = s0;
        int s1;
        if (v + 1 < NVOX) s1 = vtmp[v + 1] + bsum[(v + 1) >> 8];
        else              s1 = NPTS;
        for (int j = s0; j < s1; j++) vsorted[j] = v;
        if ((s0 >> 4) != ((s1 - 1) >> 4)) {   // spans a 16-pt window boundary
            float4 z4 = {0.f, 0.f, 0.f, 0.f};
            float4* pv = (float4*)&v0[(long)v * 64];
            float4* py = (float4*)&y1m[(long)v * 64];
#pragma unroll
            for (int u = 0; u < 16; u++) { pv[u] = z4; py[u] = z4; }
        }
    }
    if (v == 0) vstart[NVOX] = NPTS;
}

// ---- K2: Gram stats (in-register, fully unrolled) + counting-sort scatter
// of ONLY the point index (4B/pt; vsorted comes from scan3's streaming fill).
__global__ __launch_bounds__(256, 4)
void k_prep(const __hip_bfloat16* __restrict__ feat,
            const int* __restrict__ inv,
            const int* __restrict__ coors,
            const float* __restrict__ acc4,
            int* __restrict__ voff,
            int* __restrict__ ord,
            float* __restrict__ gram) {
    __shared__ float gs[72];
    int t = threadIdx.x;
    if (t < 72) gs[t] = 0.0f;
    __syncthreads();

    float sx[10], sxx[55];
#pragma unroll
    for (int a = 0; a < 10; a++) sx[a] = 0.0f;
#pragma unroll
    for (int a = 0; a < 55; a++) sxx[a] = 0.0f;

    for (long i = (long)blockIdx.x * 256 + t; i < NPTS; i += (long)GBLK * 256) {
        int v = inv[i];
        float xv[10];
        compute_x(feat, acc4, coors, i, v, xv);
        int idx = 0;
#pragma unroll
        for (int a = 0; a < 10; a++) {
            sx[a] += xv[a];
#pragma unroll
            for (int b = 0; b <= a; b++) sxx[idx++] += xv[a] * xv[b];
        }
        int pos = atomicAdd(&voff[v], 1);
        ord[pos] = (int)i;
    }

#pragma unroll
    for (int v = 0; v < 65; v++) {
        float s = (v < 10) ? sx[v] : sxx[v - 10];
        for (int m = 32; m >= 1; m >>= 1) s += __shfl_xor(s, m);
        if ((t & 63) == 0) atomicAdd(&gs[v], s);
    }
    __syncthreads();
    if (t < 65) atomicAdd(&gram[t], gs[t]);
}

// ---- K3: h0 = relu(bn0(y0)); sorted tile; wave 1 folds the BN0 finalize
// into LDS. Spills the h0 tile (bf16, sorted layout) for layer 1.
// Window-complete voxels plain-store their final max DIRECTLY AS BF16 (v0b,
// half the bytes — k_mfma consumes bf16 anyway); only window-spanning voxels
// use the fp32 atomicMax path (v0, zero-init'd rows). ----
__global__ __launch_bounds__(256, 6)
void k_h0max(const int* __restrict__ ord, const int* __restrict__ vsorted,
             const int* __restrict__ vstart,
             const __hip_bfloat16* __restrict__ feat,
             const float* __restrict__ acc4, const int* __restrict__ coors,
             const float* __restrict__ W0f, const float* __restrict__ gram,
             const __hip_bfloat16* __restrict__ g0,
             const __hip_bfloat16* __restrict__ be0,
             float* __restrict__ v0, unsigned short* __restrict__ v0b,
             unsigned short* __restrict__ h0t) {
    __shared__ float ht[64 * HT_LD];      // 16640 B
    __shared__ int invs[64];
    __shared__ float sc0s[64], bi0s[64];  // total ~17.4 KB
    int t = threadIdx.x, w = t >> 6, l = t & 63;
    int base = blockIdx.x * 64;
    int i = ord[base + l];
    int v = vsorted[base + l];
    if (w == 0) invs[l] = v;

    float xv[10];
    compute_x(feat, acc4, coors, (long)i, v, xv);

    if (w == 1) {
        // BN0 finalize from Gram (per-block redundant, ~100 FMA — trivial)
        int c = l;
        float wr[10];
#pragma unroll
        for (int k = 0; k < 10; k++) wr[k] = W0f[c * 10 + k];
        float sum = 0.0f, sq = 0.0f;
#pragma unroll
        for (int a = 0; a < 10; a++) {
            sum += wr[a] * gram[a];
            float ta = 0.0f;
#pragma unroll
            for (int b = 0; b < 10; b++) {
                int hi = (a >= b) ? a : b, lo = (a >= b) ? b : a;
                ta += wr[b] * gram[10 + hi * (hi + 1) / 2 + lo];
            }
            sq += wr[a] * ta;
        }
        float mu  = sum * (1.0f / NPTS);
        float var = sq * (1.0f / NPTS) - mu * mu;
        float g   = b2f(g0[c]) * rsqrtf(var + EPSB);
        sc0s[c] = g;
        bi0s[c] = b2f(be0[c]) - mu * g;
    }
    __syncthreads();

    int cw = w * 16;
#pragma unroll
    for (int j = 0; j < 16; j++) {
        int c = cw + j;
        float y = 0.0f;
#pragma unroll
        for (int k = 0; k < 10; k++) y += xv[k] * W0f[c*10 + k];
        ht[l * HT_LD + c] = fmaxf(sc0s[c] * y + bi0s[c], 0.0f);
    }
    __syncthreads();

    // spill h0 tile (bf16, sorted layout)
#pragma unroll
    for (int u = 0; u < 2; u++) {
        int idx = t + u * 256;          // 0..511, coalesced uint4 per thread
        int pt2 = idx >> 3;
        int c0 = (idx & 7) * 8;
        const float* src = &ht[pt2 * HT_LD + c0];
        float4 a  = *(const float4*)src;
        float4 b4 = *(const float4*)(src + 4);
        uint4 o;
        o.x = (unsigned int)bf16u(a.x)  | ((unsigned int)bf16u(a.y)  << 16);
        o.y = (unsigned int)bf16u(a.z)  | ((unsigned int)bf16u(a.w)  << 16);
        o.z = (unsigned int)bf16u(b4.x) | ((unsigned int)bf16u(b4.y) << 16);
        o.w = (unsigned int)bf16u(b4.z) | ((unsigned int)bf16u(b4.w) << 16);
        *(uint4*)&h0t[(long)(base + pt2) * 64 + c0] = o;
    }

    // lane = channel; wave walks its 16 sorted points; run-combine.
    // Window-complete voxel -> final bf16 plain store (v0b, coalesced u16);
    // window-spanning -> fp32 atomicMax (v0).
    unsigned int mk = 0u;
#pragma unroll
    for (int j = 0; j < 16; j++) {
        int p = cw + j;
        unsigned int hb = __float_as_uint(ht[p * HT_LD + l]);
        mk = (hb > mk) ? hb : mk;
        if (j == 15 || invs[p + 1] != invs[p]) {
            int vv = invs[p];
            int s0 = vstart[vv], s1 = vstart[vv + 1];
            if (s0 >= base + cw && s1 <= base + cw + 16)
                v0b[(long)vv * 64 + l] = bf16u(__uint_as_float(mk));
            else
                atomicMax((unsigned int*)&v0[(long)vv * 64 + l], mk);
            mk = 0u;
        }
    }
}

// ---- K4: layer-1 MFMA over sorted tiles. h0 half of x1 is a coalesced tile
// copy from h0t; v0 half: window-complete voxels copy bf16 rows straight
// from v0b (no cvt); only window-spanning voxels read fp32 v0 + cvt. ----
__global__ __launch_bounds__(256, 6)
void k_mfma_stats(const int* __restrict__ vsorted,
                  const int* __restrict__ vstart,
                  const unsigned short* __restrict__ h0t,
                  const unsigned short* __restrict__ w1b,
                  const float* __restrict__ v0,
                  const unsigned short* __restrict__ v0b,
                  float* __restrict__ P1,
                  unsigned int* __restrict__ y1m) {
    __shared__ union {
        unsigned short xtb[64 * XTB_LD];
        float ht[64 * HT_LD];
    } sm;
    __shared__ int invs[64];
    int t = threadIdx.x, w = t >> 6, l = t & 63;
    int quad = l >> 4, lm = l & 15;
    int base = blockIdx.x * 64;
    if (w == 0) invs[l] = vsorted[base + l];

    bf16x8 bfrag[4];
    const uint4* wf = (const uint4*)w1b;
#pragma unroll
    for (int ks = 0; ks < 4; ks++)
        bfrag[ks] = __builtin_bit_cast(bf16x8, wf[(w * 4 + ks) * 64 + l]);

    // ---- stage x1 tile (bf16 [pt][k]): h0 half is a coalesced tile copy ----
#pragma unroll
    for (int u = 0; u < 2; u++) {
        int idx = t + u * 256;
        int pt = idx >> 3, c0 = (idx & 7) * 8;
        uint4 d = *(const uint4*)&h0t[(long)(base + pt) * 64 + c0];
        *(uint4*)&sm.xtb[pt * XTB_LD + c0] = d;
    }
    {
        // v0 half: 4 lanes/pt; bf16 source for window-complete voxels
        int p = t >> 2, q = t & 3;
        int vv = vsorted[base + p];
        int s0 = vstart[vv], s1 = vstart[vv + 1];
        if ((s0 >> 4) == ((s1 - 1) >> 4)) {
            const uint4* src = (const uint4*)&v0b[(long)vv * 64 + q * 16];
            *(uint4*)&sm.xtb[p * XTB_LD + 64 + q * 16]     = src[0];
            *(uint4*)&sm.xtb[p * XTB_LD + 64 + q * 16 + 8] = src[1];
        } else {
            const float4* src = (const float4*)&v0[(long)vv * 64 + q * 16];
#pragma unroll
            for (int u = 0; u < 4; u++) {
                float4 f4 = src[u];
                ushort4 s4 = { bf16u(f4.x), bf16u(f4.y), bf16u(f4.z), bf16u(f4.w) };
                *(ushort4*)&sm.xtb[p * XTB_LD + 64 + q * 16 + 4 * u] = s4;
            }
        }
    }
    __syncthreads();

    // ---- MFMA ----
    f32x4 acc[4];
#pragma unroll
    for (int pg = 0; pg < 4; pg++) acc[pg] = (f32x4){0.f, 0.f, 0.f, 0.f};
#pragma unroll
    for (int ks = 0; ks < 4; ks++) {
#pragma unroll
        for (int pg = 0; pg < 4; pg++) {
            const uint4* ap = (const uint4*)&sm.xtb[(pg * 16 + lm) * XTB_LD + ks * 32 + quad * 8];
            bf16x8 a = __builtin_bit_cast(bf16x8, *ap);
            acc[pg] = __builtin_amdgcn_mfma_f32_16x16x32_bf16(a, bfrag[ks], acc[pg], 0, 0, 0);
        }
    }

    // ---- stats from accumulators ----
    float ssum = 0.0f, ssq = 0.0f;
#pragma unroll
    for (int pg = 0; pg < 4; pg++) {
#pragma unroll
        for (int r = 0; r < 4; r++) {
            float y = acc[pg][r];
            ssum += y; ssq += y * y;
        }
    }
    __syncthreads();   // all xtb reads done -> safe to overwrite with ht

    // raw y1 -> LDS transpose (C layout: row = quad*4+r, col = lm)
#pragma unroll
    for (int pg = 0; pg < 4; pg++) {
#pragma unroll
        for (int r = 0; r < 4; r++)
            sm.ht[(pg * 16 + quad * 4 + r) * HT_LD + w * 16 + lm] = acc[pg][r];
    }
    __syncthreads();

    // lane = channel; wave walks its 16 sorted points; plain-store/atomic split
    unsigned int mk = 0u;
    int cw = w * 16;
#pragma unroll
    for (int j = 0; j < 16; j++) {
        int p = cw + j;
        unsigned int k2 = fkey(sm.ht[p * HT_LD + l]);
        mk = (k2 > mk) ? k2 : mk;
        if (j == 15 || invs[p + 1] != invs[p]) {
            int vv = invs[p];
            int s0 = vstart[vv], s1 = vstart[vv + 1];
            unsigned int* dst = &y1m[(long)vv * 64 + l];
            if (s0 >= base + cw && s1 <= base + cw + 16)
                *dst = mk;
            else
                atomicMax(dst, mk);
            mk = 0u;
        }
    }

    ssum += __shfl_xor(ssum, 16); ssq += __shfl_xor(ssq, 16);
    ssum += __shfl_xor(ssum, 32); ssq += __shfl_xor(ssq, 32);
    if (l < 16) {
        int slot = blockIdx.x & 31;
        atomicAdd(&P1[slot * 128 + w * 16 + lm], ssum);
        atomicAdd(&P1[slot * 128 + 64 + w * 16 + lm], ssq);
    }
}

// ---- K5: emit output with INLINE BN1 finalize (per-block redundant P1 reduce).
// feats = relu(bn1(decode(y1max))); coors bf16-rounded. Grid-stride, 512 blocks.
#define OUTBLK 512
__global__ __launch_bounds__(256)
void k_out(const unsigned int* __restrict__ y1m,
           const float* __restrict__ P1,
           const __hip_bfloat16* __restrict__ gamma,
           const __hip_bfloat16* __restrict__ beta,
           const int* __restrict__ coors,
           float* __restrict__ out) {
    __shared__ float sc1s[64], bi1s[64];
    int t = threadIdx.x;
    if (t < 64) {
        float sum = 0.0f, sq = 0.0f;
        for (int s = 0; s < 32; s++) {
            sum += P1[s*128 + t];
            sq  += P1[s*128 + 64 + t];
        }
        float mu  = sum * (1.0f / NPTS);
        float var = sq * (1.0f / NPTS) - mu * mu;
        float g   = b2f(gamma[t]) * rsqrtf(var + EPSB);
        sc1s[t] = g;
        bi1s[t] = b2f(beta[t]) - mu * g;
    }
    __syncthreads();

    const long n4feat = (long)NVOX * 16;   // uint4 chunks of y1m
    const long n4all  = n4feat + NVOX;     // + int4 chunks of coors
    const long nfeat  = (long)NVOX * 64;
    for (long idx = (long)blockIdx.x * 256 + t; idx < n4all; idx += (long)OUTBLK * 256) {
        if (idx < n4feat) {
            uint4 kk = ((const uint4*)y1m)[idx];
            int c0 = (int)((idx * 4) & 63);
            float4 o;
            o.x = fmaxf(sc1s[c0+0] * funkey(kk.x) + bi1s[c0+0], 0.0f);
            o.y = fmaxf(sc1s[c0+1] * funkey(kk.y) + bi1s[c0+1], 0.0f);
            o.z = fmaxf(sc1s[c0+2] * funkey(kk.z) + bi1s[c0+2], 0.0f);
            o.w = fmaxf(sc1s[c0+3] * funkey(kk.w) + bi1s[c0+3], 0.0f);
            ((float4*)out)[idx] = o;
        } else {
            long vi = idx - n4feat;
            int4 c4 = ((const int4*)coors)[vi];
            float4 o;
            o.x = b2f(__float2bfloat16((float)c4.x));
            o.y = b2f(__float2bfloat16((float)c4.y));
            o.z = b2f(__float2bfloat16((float)c4.z));
            o.w = b2f(__float2bfloat16((float)c4.w));
            ((float4*)(out + nfeat))[vi] = o;
        }
    }
}

extern "C" void kernel_launch(void* const* d_in, const int* in_sizes, int n_in,
                              void* d_out, int out_size, void* d_ws, size_t ws_size,
                              hipStream_t stream) {
    const __hip_bfloat16* feat = (const __hip_bfloat16*)d_in[0];
    const __hip_bfloat16* W0   = (const __hip_bfloat16*)d_in[1];
    const __hip_bfloat16* g0   = (const __hip_bfloat16*)d_in[2];
    const __hip_bfloat16* be0  = (const __hip_bfloat16*)d_in[3];
    const __hip_bfloat16* W1   = (const __hip_bfloat16*)d_in[4];
    const __hip_bfloat16* g1   = (const __hip_bfloat16*)d_in[5];
    const __hip_bfloat16* be1  = (const __hip_bfloat16*)d_in[6];
    const int* inv   = (const int*)d_in[7];
    const int* coors = (const int*)d_in[8];
    float* out = (float*)d_out;

    float* ws    = (float*)d_ws;
    float* acc4  = ws + OFF_ACC4;
    float* gram  = ws + OFF_GRAM;
    float* P1    = ws + OFF_P1;
    float* v0    = ws + OFF_V0;
    unsigned int* y1m = (unsigned int*)(ws + OFF_Y1M);
    int* vtmp    = (int*)(ws + OFF_VTMP);
    int* bsum    = (int*)(ws + OFF_BSUM);
    int* voff    = (int*)(ws + OFF_VOFF);
    int* vstart  = (int*)(ws + OFF_VSTART);
    int* ord     = (int*)(ws + OFF_ORD);
    int* vsorted = (int*)(ws + OFF_VS);
    float* W0f   = ws + OFF_W0F;
    unsigned short* w1b = (unsigned short*)(ws + OFF_W1B);
    unsigned short* h0t = (unsigned short*)(ws + OFF_H0T);
    unsigned short* v0b = (unsigned short*)(ws + OFF_V0B);

    // Only atomic-accumulated buffers need zeroing (acc4, gram, P1);
    // v0/y1m spanning rows are zeroed selectively by k_scan3.
    hipMemsetAsync(ws, 0, (size_t)ZERO_FLOATS * sizeof(float), stream);

    k_vsum<<<6251, 256, 0, stream>>>(feat, inv, acc4, W0, W1, W0f, w1b);
    k_scan1<<<NBLK_SCAN, 256, 0, stream>>>(acc4, vtmp, bsum);
    k_scan2<<<1, 512, 0, stream>>>(bsum);
    k_scan3<<<NBLK_SCAN, 256, 0, stream>>>(vtmp, bsum, voff, vstart, vsorted, v0, y1m);
    k_prep<<<GBLK, 256, 0, stream>>>(feat, inv, coors, acc4, voff, ord, gram);
    k_h0max<<<NTILE, 256, 0, stream>>>(ord, vsorted, vstart, feat, acc4, coors,
                                       W0f, gram, g0, be0, v0, v0b, h0t);
    k_mfma_stats<<<NTILE, 256, 0, stream>>>(vsorted, vstart, h0t, w1b, v0, v0b, P1, y1m);
    k_out<<<OUTBLK, 256, 0, stream>>>(y1m, P1, g1, be1, coors, out);
}